// Round 4
// baseline (84.425 us; speedup 1.0000x reference)
//
#include <hip/hip_runtime.h>
#include <hip/hip_bf16.h>
#include <math.h>

// Problem constants (fixed by setup_inputs): b=2, n=8192, c=64, k=32
#define NPTS   8192
#define NBATCH 2
#define NQ     (NPTS * NBATCH)   // 16384 total query points
#define KNB    32                // neighbors per query
#define CFEAT  64
#define QW     4                 // queries per wave
#define NWAVES 4                 // waves per block
#define QB     (QW * NWAVES)     // 16 queries per block
#define CHUNK  2048              // staged points per LDS chunk
#define NBLK1  (NQ / QB)         // 1024 blocks for kernel 1
#define BN_EPS 1e-5f

// ws layout (in floats)
#define WS_H     0                        // h values: NQ*3*KNB = 1,572,864 floats
#define WS_PART  (NQ * 3 * KNB)           // partial sums: 6 * NBLK1 floats
#define WS_STATS (WS_PART + 6 * NBLK1)    // mean[3], inv[3]

// ---------------------------------------------------------------------------
// Kernel 1: ball query (first-K in index order) + h = w1*rel + BN partial sums
// One wave handles QW queries; lanes parallel over candidate j.
// SELECTION IN FLOAT64: d2 = (sq_i + sq_j) - 2*dot computed in double.
// f64 rounding (~1e-15) vs the selection band makes the neighbor sets
// bit-stable against any reasonable reference backend; self-distance is
// exactly 0.0 (sq and dot use identical FMA chains).
// ---------------------------------------------------------------------------
__global__ __launch_bounds__(256) void k1_ballquery(
    const float* __restrict__ pos, const float* __restrict__ w1,
    const float* __restrict__ radius, float* __restrict__ ws)
{
    __shared__ float4 spos[CHUNK];        // xyz (f32), 32 KB
    __shared__ int    slist[QB][KNB];     // neighbor index lists, 2 KB
    __shared__ float  sred[NWAVES * 6];   // block reduction scratch

    const int tid  = threadIdx.x;
    const int lane = tid & 63;
    const int wave = tid >> 6;
    const int qbase = blockIdx.x * QB;          // global query base
    const int batch = qbase / NPTS;             // whole block in one batch (QB | NPTS)
    const float* bpos = pos + (size_t)batch * NPTS * 3;
    const int qloc0 = (qbase - batch * NPTS) + wave * QW;

    // Load this wave's query positions (wave-uniform); keep f32 + f64 copies
    float  qx[QW], qy[QW], qz[QW];
    double qxd[QW], qyd[QW], qzd[QW], qsqd[QW];
#pragma unroll
    for (int q = 0; q < QW; ++q) {
        const float* pq = bpos + (size_t)(qloc0 + q) * 3;
        float x = pq[0], y = pq[1], z = pq[2];
        qx[q] = x; qy[q] = y; qz[q] = z;
        double xd = (double)x, yd = (double)y, zd = (double)z;
        qxd[q] = xd; qyd[q] = yd; qzd[q] = zd;
        qsqd[q] = fma(zd, zd, fma(yd, yd, xd * xd));
    }
    const double rd  = (double)radius[0];
    const double r2d = rd * rd;

    int cnt[QW];
#pragma unroll
    for (int q = 0; q < QW; ++q) cnt[q] = 0;

    for (int cbase = 0; cbase < NPTS; cbase += CHUNK) {
        __syncthreads();
        // stage chunk (f32 xyz)
        for (int p = tid; p < CHUNK; p += 256) {
            const float* pp = bpos + (size_t)(cbase + p) * 3;
            spos[p] = make_float4(pp[0], pp[1], pp[2], 0.0f);
        }
        __syncthreads();

        for (int w = 0; w < CHUNK / 64; ++w) {
            float4 pj = spos[w * 64 + lane];
            // convert candidate to f64 once, reuse across QW queries
            double xj = (double)pj.x, yj = (double)pj.y, zj = (double)pj.z;
            double sqj = fma(zj, zj, fma(yj, yj, xj * xj));
            const int j0 = cbase + w * 64;
#pragma unroll
            for (int q = 0; q < QW; ++q) {
                double dot = fma(zj, qzd[q], fma(yj, qyd[q], xj * qxd[q]));
                double t   = qsqd[q] + sqj;
                double d2  = t - 2.0 * dot;
                unsigned long long bal = __ballot(d2 < r2d);
                // uniform in-order extraction (~0.5 hits per word on average)
                while (bal != 0ull && cnt[q] < KNB) {
                    int b = __ffsll((long long)bal) - 1;
                    if (lane == 0) slist[wave * QW + q][cnt[q]] = j0 + b;
                    cnt[q]++;
                    bal &= bal - 1ull;
                }
            }
        }
    }
    __syncthreads();   // make lane-0 slist writes visible wave/block-wide

    // Epilogue: compute h for K slots (pad with first hit), store + local stats
    float w1r[9];
#pragma unroll
    for (int i = 0; i < 9; ++i) w1r[i] = w1[i];   // w1[d][c] row-major

    float ls0 = 0.f, ls1 = 0.f, ls2 = 0.f;
    float lq0 = 0.f, lq1 = 0.f, lq2 = 0.f;

#pragma unroll
    for (int q = 0; q < QW; ++q) {
        if (lane < KNB) {
            const int qslot = wave * QW + q;
            const int kk = lane;
            // self is always a hit (d2==0.0 exactly) so cnt >= 1
            int j = slist[qslot][kk < cnt[q] ? kk : 0];
            const float* pj = bpos + (size_t)j * 3;
            float rx = __fsub_rn(pj[0], qx[q]);
            float ry = __fsub_rn(pj[1], qy[q]);
            float rz = __fsub_rn(pj[2], qz[q]);
            // h = rel . w1[d,:]  — GEMM FMA chain
            float h0 = fmaf(rz, w1r[2], fmaf(ry, w1r[1], __fmul_rn(rx, w1r[0])));
            float h1 = fmaf(rz, w1r[5], fmaf(ry, w1r[4], __fmul_rn(rx, w1r[3])));
            float h2 = fmaf(rz, w1r[8], fmaf(ry, w1r[7], __fmul_rn(rx, w1r[6])));
            const int qg = qbase + wave * QW + q;
            float* hout = ws + WS_H + (size_t)qg * 3 * KNB;
            hout[0 * KNB + kk] = h0;
            hout[1 * KNB + kk] = h1;
            hout[2 * KNB + kk] = h2;
            ls0 += h0; ls1 += h1; ls2 += h2;
            lq0 += h0 * h0; lq1 += h1 * h1; lq2 += h2 * h2;
        }
    }

    // wave-level reduction (lanes >= 32 contribute 0)
#pragma unroll
    for (int m = 1; m < 64; m <<= 1) {
        ls0 += __shfl_xor(ls0, m); ls1 += __shfl_xor(ls1, m); ls2 += __shfl_xor(ls2, m);
        lq0 += __shfl_xor(lq0, m); lq1 += __shfl_xor(lq1, m); lq2 += __shfl_xor(lq2, m);
    }
    if (lane == 0) {
        sred[wave * 6 + 0] = ls0; sred[wave * 6 + 1] = ls1; sred[wave * 6 + 2] = ls2;
        sred[wave * 6 + 3] = lq0; sred[wave * 6 + 4] = lq1; sred[wave * 6 + 5] = lq2;
    }
    __syncthreads();
    if (tid == 0) {
#pragma unroll
        for (int c = 0; c < 6; ++c) {
            float s = sred[c] + sred[6 + c] + sred[12 + c] + sred[18 + c];
            ws[WS_PART + c * NBLK1 + blockIdx.x] = s;   // deterministic partials
        }
    }
}

// ---------------------------------------------------------------------------
// Kernel 2: reduce per-block partials -> mean[3], inv[3] = rsqrt(var+eps)
// ---------------------------------------------------------------------------
__global__ __launch_bounds__(256) void k2_stats(float* __restrict__ ws)
{
    __shared__ float red[256];
    __shared__ float tot[6];
    const int tid = threadIdx.x;
    for (int c = 0; c < 6; ++c) {
        float v = 0.f;
        for (int i = tid; i < NBLK1; i += 256) v += ws[WS_PART + c * NBLK1 + i];
        red[tid] = v;
        __syncthreads();
        for (int s = 128; s > 0; s >>= 1) {
            if (tid < s) red[tid] += red[tid + s];
            __syncthreads();
        }
        if (tid == 0) tot[c] = red[0];
        __syncthreads();
    }
    if (tid == 0) {
        const double Ntot = (double)((long long)NQ * KNB);
#pragma unroll
        for (int d = 0; d < 3; ++d) {
            double mean = (double)tot[d] / Ntot;
            double var  = (double)tot[3 + d] / Ntot - mean * mean;
            float inv   = (float)(1.0 / sqrt(var + (double)BN_EPS));
            ws[WS_STATS + d]     = (float)mean;
            ws[WS_STATS + 3 + d] = inv;
        }
    }
}

// ---------------------------------------------------------------------------
// Kernel 3: g = relu(((h-mean)*inv)*gamma + beta)  (reference op order)
//           pe = max_k (FMA-chain g.w2[e] + b2[e]);  out = x + pe
// One wave per query: lanes 0..31 produce g (LDS), all 64 lanes = output chans
// ---------------------------------------------------------------------------
__global__ __launch_bounds__(256) void k3_mlp(
    const float* __restrict__ ws, const float* __restrict__ gamma,
    const float* __restrict__ beta, const float* __restrict__ w2,
    const float* __restrict__ b2, const float* __restrict__ x,
    float* __restrict__ out)
{
    __shared__ float g[4][KNB][3];
    const int tid  = threadIdx.x;
    const int lane = tid & 63;
    const int wave = tid >> 6;
    const int qg = blockIdx.x * 4 + wave;

    const float m0 = ws[WS_STATS + 0], m1 = ws[WS_STATS + 1], m2 = ws[WS_STATS + 2];
    const float i0 = ws[WS_STATS + 3], i1 = ws[WS_STATS + 4], i2 = ws[WS_STATS + 5];
    const float g0c = gamma[0], g1c = gamma[1], g2c = gamma[2];
    const float b0c = beta[0],  b1c = beta[1],  b2c = beta[2];

    if (lane < KNB) {
        const float* hin = ws + WS_H + (size_t)qg * 3 * KNB;
        float h0 = hin[0 * KNB + lane];
        float h1 = hin[1 * KNB + lane];
        float h2 = hin[2 * KNB + lane];
        // ((h - mean) * inv) * gamma + beta, stepwise rounded
        float n0 = __fadd_rn(__fmul_rn(__fmul_rn(__fsub_rn(h0, m0), i0), g0c), b0c);
        float n1 = __fadd_rn(__fmul_rn(__fmul_rn(__fsub_rn(h1, m1), i1), g1c), b1c);
        float n2 = __fadd_rn(__fmul_rn(__fmul_rn(__fsub_rn(h2, m2), i2), g2c), b2c);
        g[wave][lane][0] = fmaxf(n0, 0.0f);
        g[wave][lane][1] = fmaxf(n1, 0.0f);
        g[wave][lane][2] = fmaxf(n2, 0.0f);
    }
    __syncthreads();

    const float w20 = w2[lane * 3 + 0];
    const float w21 = w2[lane * 3 + 1];
    const float w22 = w2[lane * 3 + 2];
    const float bias = b2[lane];
    float m = -INFINITY;
#pragma unroll 4
    for (int kk = 0; kk < KNB; ++kk) {
        float ga = g[wave][kk][0], gb = g[wave][kk][1], gc = g[wave][kk][2];
        float pe = __fadd_rn(fmaf(gc, w22, fmaf(gb, w21, __fmul_rn(ga, w20))), bias);
        m = fmaxf(m, pe);
    }
    const size_t o = (size_t)qg * CFEAT + lane;
    out[o] = __fadd_rn(x[o], m);
}

// ---------------------------------------------------------------------------
extern "C" void kernel_launch(void* const* d_in, const int* in_sizes, int n_in,
                              void* d_out, int out_size, void* d_ws, size_t ws_size,
                              hipStream_t stream) {
    (void)in_sizes; (void)n_in; (void)out_size; (void)ws_size;
    const float* pos    = (const float*)d_in[0];
    const float* x      = (const float*)d_in[1];
    const float* w1     = (const float*)d_in[2];
    const float* gamma  = (const float*)d_in[3];
    const float* beta   = (const float*)d_in[4];
    const float* w2     = (const float*)d_in[5];
    const float* b2     = (const float*)d_in[6];
    const float* radius = (const float*)d_in[7];
    // d_in[8] = k, fixed at 32 (compile-time KNB)
    float* out = (float*)d_out;
    float* ws  = (float*)d_ws;

    hipLaunchKernelGGL(k1_ballquery, dim3(NBLK1), dim3(256), 0, stream,
                       pos, w1, radius, ws);
    hipLaunchKernelGGL(k2_stats, dim3(1), dim3(256), 0, stream, ws);
    hipLaunchKernelGGL(k3_mlp, dim3(NQ / 4), dim3(256), 0, stream,
                       ws, gamma, beta, w2, b2, x, out);
}